// Round 10
// baseline (1443.045 us; speedup 1.0000x reference)
//
#include <hip/hip_runtime.h>
#include <hip/hip_bf16.h>

#define NUMC 2048

typedef short bf16x8 __attribute__((ext_vector_type(8)));
typedef float f32x4 __attribute__((ext_vector_type(4)));
typedef int i32x8 __attribute__((ext_vector_type(8)));

__device__ __forceinline__ unsigned short f2bf(float f) {
  unsigned int u = __float_as_uint(f);
  u = u + 0x7fffu + ((u >> 16) & 1u);
  return (unsigned short)(u >> 16);
}
__device__ __forceinline__ float bf2f(unsigned short s) {
  return __uint_as_float(((unsigned int)s) << 16);
}
__device__ __forceinline__ float sigm(float x) {
  return __fdividef(1.f, 1.f + __expf(-x));
}
__device__ __forceinline__ float tanh_(float x) {
  float ax = fabsf(x);
  float s = __expf(-2.f * ax);
  float ta = __fdividef(1.f - s, 1.f + s);
  return copysignf(ta, x);
}
__device__ __forceinline__ unsigned int pack2(unsigned short a, unsigned short b) {
  return (unsigned int)a | ((unsigned int)b << 16);
}
// async 16B/lane global->LDS (lds dest = wave-uniform base + lane*16)
__device__ __forceinline__ void gll16(const void* g, void* lds) {
  __builtin_amdgcn_global_load_lds(
      (const __attribute__((address_space(1))) unsigned int*)g,
      (__attribute__((address_space(3))) unsigned int*)lds, 16, 0, 0);
}

// ---- pack B into linear MFMA slabs: Bp[((ks*Ng + ng)*64 + l)*8 + j] =
//      bf16(W[(ng*16 + (l&15))*320 + ks*32 + (l>>4)*8 + j]);  ks=0..9 (K=320)
__global__ void k_pack_b(const float* __restrict__ W, unsigned short* __restrict__ Bp,
                         int Nmask, int logNg) {
  int e = blockIdx.x * 256 + threadIdx.x;  // N*320 total
  int j = e & 7;
  int l = (e >> 3) & 63;
  int ng = (e >> 9) & Nmask;
  int ks = e >> (9 + logNg);
  int n = ng * 16 + (l & 15);
  int k = ks * 32 + (l >> 4) * 8 + j;
  Bp[e] = f2bf(W[n * 320 + k]);
}

// ---- per-gate-row scale for fp8 quantization of W_hh
__global__ void k_rowmax(const float* __restrict__ Whh, float* __restrict__ fs) {
  int row = blockIdx.x;
  int l = threadIdx.x;  // 64
  float m = 0.f;
#pragma unroll
  for (int i = 0; i < 4; ++i) m = fmaxf(m, fabsf(Whh[row * 256 + i * 64 + l]));
#pragma unroll
  for (int off = 32; off > 0; off >>= 1) m = fmaxf(m, __shfl_xor(m, off));
  if (l == 0) fs[row] = (m > 0.f ? m : 1.f) * (1.f / 192.f);
}

// ---- pack W_hh into fp8 e4m3 fragments for mfma_scale 16x16x128:
// frag = ((w*2+nt)*4+g)*2+kt ; lane l holds 32 bytes: k = kt*128 + (l>>4)*32 + 0..31
__global__ void k_pack_whh_mx(const float* __restrict__ Whh, const float* __restrict__ fs,
                              long long* __restrict__ P) {
  int e = blockIdx.x * 256 + threadIdx.x;  // 8192 lane-slots
  int l = e & 63;
  int frag = e >> 6;
  int kt = frag & 1;
  int g = (frag >> 1) & 3;
  int nt = (frag >> 3) & 1;
  int w = frag >> 4;
  int gr = g * 256 + w * 32 + nt * 16 + (l & 15);
  int k0 = kt * 128 + (l >> 4) * 32;
  float inv = __fdividef(1.f, fs[gr]);
#pragma unroll
  for (int q = 0; q < 4; ++q) {
    unsigned long long v = 0;
#pragma unroll
    for (int jj = 0; jj < 4; ++jj) {
      float w0 = Whh[gr * 256 + k0 + q * 8 + 2 * jj] * inv;
      float w1 = Whh[gr * 256 + k0 + q * 8 + 2 * jj + 1] * inv;
      int pk = __builtin_amdgcn_cvt_pk_fp8_f32(w0, w1, 0, 0);
      v |= (unsigned long long)(unsigned)(pk & 0xffff) << (16 * jj);
    }
    P[(size_t)e * 4 + q] = (long long)v;
  }
}

// ---- theta = bf16(E[x]*Cct), C2 = bf16(Cct_shifted), packed combos
__global__ void k_theta(const int* __restrict__ q, const int* __restrict__ r,
                        const int* __restrict__ rg_, const int* __restrict__ sg_,
                        const int* __restrict__ pc_, const int* __restrict__ srg_,
                        const int* __restrict__ ssg_, const int* __restrict__ spc_,
                        const float* __restrict__ E, const float* __restrict__ Wc,
                        unsigned short* __restrict__ theta, unsigned short* __restrict__ C2,
                        int* __restrict__ combo, int* __restrict__ combo2) {
  int tid = threadIdx.x;
  int row = blockIdx.x * 8 + (tid >> 5);
  int u0 = (tid & 31) * 8;
  int x = q[row] + NUMC * r[row];
  int rg = rg_[row], sg = sg_[row], pc = pc_[row];
  int g1 = srg_[row], g2 = ssg_[row], g3 = spc_[row];
  const float* e = E + (size_t)x * 256 + u0;
  unsigned short tv[8], cv[8];
#pragma unroll
  for (int i = 0; i < 8; ++i) {
    const float* wr = Wc + (size_t)(u0 + i) * 64;
    float cct = wr[rg] + wr[16 + sg] + wr[32 + pc];
    float cc2 = wr[g1] + wr[16 + g2] + wr[32 + g3];
    tv[i] = f2bf(e[i] * cct);
    cv[i] = f2bf(cc2);
  }
  uint4 tvec = {pack2(tv[0], tv[1]), pack2(tv[2], tv[3]), pack2(tv[4], tv[5]), pack2(tv[6], tv[7])};
  uint4 cvec = {pack2(cv[0], cv[1]), pack2(cv[2], cv[3]), pack2(cv[4], cv[5]), pack2(cv[6], cv[7])};
  *(uint4*)(theta + (size_t)row * 256 + u0) = tvec;
  *(uint4*)(C2 + (size_t)row * 256 + u0) = cvec;
  if ((tid & 31) == 0) {
    combo[row] = (rg * 16 + sg) * 32 + pc;
    combo2[row] = (g1 * 16 + g2) * 32 + g3;
  }
}

__device__ __forceinline__ uint4 onehot8(int k0, int rg, int sg, int pc) {
  unsigned vv[8];
#pragma unroll
  for (int j = 0; j < 8; ++j) {
    int k = k0 + j;
    vv[j] = (k == rg || k == sg || k == pc) ? 0x3F80u : 0u;
  }
  uint4 rr;
  rr.x = vv[0] | (vv[1] << 16);
  rr.y = vv[2] | (vv[3] << 16);
  rr.z = vv[4] | (vv[5] << 16);
  rr.w = vv[6] | (vv[7] << 16);
  return rr;
}

// ---- 128x128xK=320 bf16 MFMA GEMM, double-buffered global_load_lds pipeline.
// K 0..255 async-staged from A; K 256..319 synthesized one-hot into next buffer.
// One barrier per K-step; STAGE(ks+1) issued before compute(ks) so load latency
// hides under the MFMA phase (T3 minimum 2-phase template).
// MODE 0: xg = [A|ct]*B^T + b_ih + b_hh -> bf16.  MODE 1: y = sigmoid(..+b_out) -> f32
template <int NTOT, int MODE, int LOGGX>
__global__ __launch_bounds__(256) void k_gemm(
    const unsigned short* __restrict__ A, const unsigned short* __restrict__ Bp,
    const int* __restrict__ combo, const float* __restrict__ bias1,
    const float* __restrict__ bias2, void* __restrict__ Out) {
  __shared__ __align__(16) unsigned short As[2][4096];  // 2 x 8 slabs [lane64][8]
  __shared__ __align__(16) unsigned short Bs[2][4096];
  const int tid = threadIdx.x;
  const int w = tid >> 6, l = tid & 63;
  const int wm = w >> 1, wn = w & 1;
  constexpr int NG = NTOT / 16;

  int id = blockIdx.y * (1 << LOGGX) + blockIdx.x;
  int Nbase = ((id >> 3) & ((1 << LOGGX) - 1)) * 128;
  int Mbase = ((((id >> (3 + LOGGX)) << 3) | (id & 7))) * 128;

  f32x4 acc[4][4];
#pragma unroll
  for (int i = 0; i < 4; ++i)
#pragma unroll
    for (int j = 0; j < 4; ++j) acc[i][j] = (f32x4){0.f, 0.f, 0.f, 0.f};

  // staging addresses: wave w owns slabs 2w, 2w+1 of both A and B
  const unsigned short* gA = A + (size_t)(Mbase + (2 * w) * 16 + (l & 15)) * 256 + (l >> 4) * 8;
  const unsigned short* gB = Bp + ((size_t)(Nbase / 16 + 2 * w) * 64 + l) * 8;

  // one-hot synth params (K tail)
  const int arow = tid >> 1;
  const int agp = (tid & 1) * 2;
  const int a_ch = arow >> 4;
  const int a_ls0 = (arow & 15) | (agp << 4);
  const int a_ls1 = (arow & 15) | ((agp + 1) << 4);
  const int cmb = combo[Mbase + arow];
  const int rg = cmb >> 9, sg = 16 + ((cmb >> 5) & 15), pc = 32 + (cmb & 31);

  // STAGE K-step ks into buffer nb
  auto STAGE = [&](int ks, int nb) {
    if (ks < 8) {
      gll16(gA + ks * 32, &As[nb][(2 * w) * 512]);
      gll16(gA + ks * 32 + 16 * 256, &As[nb][(2 * w + 1) * 512]);
    } else {
      int k0 = (ks - 8) * 32 + agp * 8;
      uint4 av0 = onehot8(k0, rg, sg, pc);
      uint4 av1 = onehot8(k0 + 8, rg, sg, pc);
      *(uint4*)&As[nb][(a_ch * 64 + a_ls0) * 8] = av0;
      *(uint4*)&As[nb][(a_ch * 64 + a_ls1) * 8] = av1;
    }
    gll16(gB + (size_t)ks * NG * 512, &Bs[nb][(2 * w) * 512]);
    gll16(gB + (size_t)ks * NG * 512 + 64 * 8, &Bs[nb][(2 * w + 1) * 512]);
  };

  STAGE(0, 0);
  __syncthreads();

  for (int ks = 0; ks < 10; ++ks) {
    const int b = ks & 1;
    if (ks < 9) STAGE(ks + 1, b ^ 1);  // issue-early: hides under MFMA below
    bf16x8 bfr[4];
#pragma unroll
    for (int ni = 0; ni < 4; ++ni)
      bfr[ni] = *(const bf16x8*)&Bs[b][((wn * 4 + ni) * 64 + l) * 8];
#pragma unroll
    for (int mi = 0; mi < 4; ++mi) {
      bf16x8 af = *(const bf16x8*)&As[b][((wm * 4 + mi) * 64 + l) * 8];
#pragma unroll
      for (int ni = 0; ni < 4; ++ni)
        acc[mi][ni] = __builtin_amdgcn_mfma_f32_16x16x32_bf16(af, bfr[ni], acc[mi][ni], 0, 0, 0);
    }
    __syncthreads();  // drains stage(ks+1); orders buffer reuse
  }

  int lh = l >> 4, col = l & 15;
  float badd[4];
#pragma unroll
  for (int ni = 0; ni < 4; ++ni) {
    int gcol = Nbase + wn * 64 + ni * 16 + col;
    badd[ni] = bias1[gcol] + (MODE == 0 ? bias2[gcol] : 0.f);
  }
#pragma unroll
  for (int mi = 0; mi < 4; ++mi) {
    int grow0 = Mbase + wm * 64 + mi * 16 + lh * 4;
#pragma unroll
    for (int rr = 0; rr < 4; ++rr) {
      int grow = grow0 + rr;
#pragma unroll
      for (int ni = 0; ni < 4; ++ni) {
        int gcol = Nbase + wn * 64 + ni * 16 + col;
        float v = acc[mi][ni][rr] + badd[ni];
        if (MODE == 0) {
          ((unsigned short*)Out)[(size_t)grow * NTOT + gcol] = f2bf(v);
        } else {
          ((float*)Out)[(size_t)grow * NTOT + gcol] = sigm(v);
        }
      }
    }
  }
}

// ---- LSTM: 256 independent blocks x 1 batch row; all 1024 gates per block.
// W_hh fp8 in VGPRs (128/lane), mfma_scale 16x16x128 with identity e8m0 scales.
// NO per-step acc reset: acc carries running sum S_t; epilogue uses p = S_t - S_{t-1}.
// Gate-level spread: lanes 0-15/32-47 compute i,f; lanes 16-31/48-63 compute g,o
// (branchless parameterized activation A/(1+e^{-s x})+B); combine via shfl_xor(16).
__global__ __launch_bounds__(512, 1) void k_lstm(
    const unsigned short* __restrict__ xg, const unsigned short* __restrict__ C2,
    const long long* __restrict__ Wq, const float* __restrict__ fs,
    unsigned short* __restrict__ h2) {
  // hq: [2 buffers][16 rows][264 bytes]; only row 0 valid, rows 1..15 stay zero
  __shared__ __align__(16) char hq[2][4224];
  const int tid = threadIdx.x;
  const int w = tid >> 6, l = tid & 63;
  const int col = l & 15;
  const int half = (l >> 4) & 1;  // 0: i,f lanes   1: g,o lanes
  const int ntsel = l >> 5;
  const int blk = blockIdx.x;  // 256 blocks

  // 16 fragments x 8 VGPR = 128 registers of fp8 weights per lane
  i32x8 wreg[2][4][2];
#pragma unroll
  for (int nt = 0; nt < 2; ++nt)
#pragma unroll
    for (int g = 0; g < 4; ++g)
#pragma unroll
      for (int kt = 0; kt < 2; ++kt)
        wreg[nt][g][kt] =
            ((const i32x8*)Wq)[(((w * 2 + nt) * 4 + g) * 2 + kt) * 64 + l];

  const int u = w * 32 + ntsel * 16 + col;  // this lane's unit
  // this lane's two gates: ga = half*2, gb = half*2+1
  const float fsa = fs[(half * 2 + 0) * 256 + u];
  const float fsb = fs[(half * 2 + 1) * 256 + u];
  // activation params for ga: sigm (A=1,B=0,s=1) on i-lanes, tanh (A=2,B=-1,s=2) on g-lanes
  const float AA = half ? 2.f : 1.f;
  const float BB = half ? -1.f : 0.f;
  const float SS = half ? 2.f : 1.f;

  // zero both hq buffers (8448 B)
  {
    uint4 zz = {0u, 0u, 0u, 0u};
    ((uint4*)hq)[tid] = zz;
    if (tid < 16) ((uint4*)hq)[512 + tid] = zz;
  }

  const unsigned bg = (unsigned)blk;
  unsigned xb = (bg << 19) + (unsigned)((half * 2) * 256 + u);  // + t*1024
  unsigned cb = (bg << 17) + (unsigned)u;                       // + t*256

  unsigned short xac = xg[xb], xbc = xg[xb + 256];
  unsigned short cc = C2[cb];  // used by g,o lanes only
  xb += 1024;                  // -> t=1

  __syncthreads();

  float cst = 0.f;
  float SoldA = 0.f, SoldB = 0.f;
  f32x4 acc[2][4];
#pragma unroll
  for (int nt = 0; nt < 2; ++nt)
#pragma unroll
    for (int g = 0; g < 4; ++g) acc[nt][g] = (f32x4){0.f, 0.f, 0.f, 0.f};

#pragma unroll 1
  for (int t = 0; t < 512; ++t) {
    const int pb = t & 1;
    // prefetch t+1 (at t=511 reads harmlessly into dead theta space)
    unsigned short xan = xg[xb], xbn = xg[xb + 256];
    unsigned short cn = C2[cb + 256];

#pragma unroll
    for (int kt = 0; kt < 2; ++kt) {
      int ab = col * 264 + kt * 128 + (l >> 4) * 32;
      uint4 a0 = *(const uint4*)&hq[pb][ab];
      uint4 a1 = *(const uint4*)&hq[pb][ab + 16];
      i32x8 av;
      av[0] = (int)a0.x; av[1] = (int)a0.y; av[2] = (int)a0.z; av[3] = (int)a0.w;
      av[4] = (int)a1.x; av[5] = (int)a1.y; av[6] = (int)a1.z; av[7] = (int)a1.w;
#pragma unroll
      for (int nt = 0; nt < 2; ++nt)
#pragma unroll
        for (int g = 0; g < 4; ++g)
          acc[nt][g] = __builtin_amdgcn_mfma_scale_f32_16x16x128_f8f6f4(
              av, wreg[nt][g][kt], acc[nt][g], 0, 0, 0, 0x7F7F7F7F, 0, 0x7F7F7F7F);
    }

    // running sums -> per-step values; redistribute to 2 gates per lane
    float m0 = __uint_as_float(
        __builtin_amdgcn_permlane32_swap(__float_as_uint(acc[0][0][0]),
                                         __float_as_uint(acc[1][0][0]), false, false)[0]);
    float m1 = __uint_as_float(
        __builtin_amdgcn_permlane32_swap(__float_as_uint(acc[0][1][0]),
                                         __float_as_uint(acc[1][1][0]), false, false)[0]);
    float m2 = __uint_as_float(
        __builtin_amdgcn_permlane32_swap(__float_as_uint(acc[0][2][0]),
                                         __float_as_uint(acc[1][2][0]), false, false)[0]);
    float m3 = __uint_as_float(
        __builtin_amdgcn_permlane32_swap(__float_as_uint(acc[0][3][0]),
                                         __float_as_uint(acc[1][3][0]), false, false)[0]);
    float mm2 = __shfl_xor(m2, 16);
    float mm3 = __shfl_xor(m3, 16);
    float a_ = half ? mm2 : m0;
    float b_ = half ? mm3 : m1;
    float pa = a_ - SoldA;
    SoldA = a_;
    float pb_ = b_ - SoldB;
    SoldB = b_;

    float va = pa * fsa + bf2f(xac);
    float vb = pb_ * fsb + bf2f(xbc);
    // ra: sigm(va) on i-lanes, tanh(va) on g-lanes (branchless); rb: sigm(vb)
    float ra = AA * __fdividef(1.f, 1.f + __expf(-SS * va)) + BB;
    float rb = sigm(vb);
    // combine on g,o lanes: si, sf come from partner (lane^16)
    float si = __shfl_xor(ra, 16);
    float sf = __shfl_xor(rb, 16);
    float cv = sf * cst + si * ra;  // valid on g,o lanes (bounded garbage elsewhere)
    cst = cv;
    float th = tanh_(cv);
    float hv = rb * th;  // o * tanh(c)
    if (half) {
      h2[cb] = f2bf(hv * bf2f(cc));
      int pk = __builtin_amdgcn_cvt_pk_fp8_f32(hv, hv, 0, 0);
      hq[pb ^ 1][u] = (char)(pk & 255);
    }
    xac = xan;
    xbc = xbn;
    cc = cn;
    xb += 1024;
    cb += 256;
    __syncthreads();
  }
}

extern "C" void kernel_launch(void* const* d_in, const int* in_sizes, int n_in,
                              void* d_out, int out_size, void* d_ws, size_t ws_size,
                              hipStream_t stream) {
  const int* q = (const int*)d_in[0];
  const int* r = (const int*)d_in[1];
  const int* rg = (const int*)d_in[2];
  const int* sg = (const int*)d_in[3];
  const int* pc = (const int*)d_in[4];
  const int* srg = (const int*)d_in[5];
  const int* ssg = (const int*)d_in[6];
  const int* spc = (const int*)d_in[7];
  const float* E = (const float*)d_in[8];
  const float* Wc = (const float*)d_in[9];
  const float* Wih = (const float*)d_in[10];
  const float* Whh = (const float*)d_in[11];
  const float* bih = (const float*)d_in[12];
  const float* bhh = (const float*)d_in[13];
  const float* Wout = (const float*)d_in[14];
  const float* bout = (const float*)d_in[15];

  char* ws = (char*)d_ws;
  unsigned short* h2 = (unsigned short*)(ws);                // 64 MB
  unsigned short* Bpih = (unsigned short*)(ws + 67108864);   // 640 KB
  unsigned short* Bpout = (unsigned short*)(ws + 67764224);  // 1.25 MB
  long long* Wq = (long long*)(ws + 69074944);               // 256 KB
  float* fs = (float*)(ws + 69337088);                       // 4 KB
  int* combo = (int*)(ws + 69341184);                        // 512 KB
  int* combo2 = (int*)(ws + 69865472);                       // 512 KB (end 70389760)

  char* dout = (char*)d_out;
  unsigned short* xg = (unsigned short*)dout;                    // 256 MB (dead until final GEMM)
  unsigned short* theta = (unsigned short*)(dout + 268435456);   // 64 MB
  unsigned short* C2 = (unsigned short*)(dout + 335544320);      // 64 MB

  k_rowmax<<<1024, 64, 0, stream>>>(Whh, fs);
  k_pack_whh_mx<<<32, 256, 0, stream>>>(Whh, fs, Wq);
  k_pack_b<<<1280, 256, 0, stream>>>(Wih, Bpih, 63, 6);
  k_pack_b<<<2560, 256, 0, stream>>>(Wout, Bpout, 127, 7);
  k_theta<<<16384, 256, 0, stream>>>(q, r, rg, sg, pc, srg, ssg, spc, E, Wc, theta, C2, combo, combo2);
  k_gemm<1024, 0, 3><<<dim3(8, 1024), 256, 0, stream>>>(theta, Bpih, combo, bih, bhh, (void*)xg);
  k_lstm<<<256, 512, 0, stream>>>(xg, C2, Wq, fs, h2);
  k_gemm<2048, 1, 4><<<dim3(16, 1024), 256, 0, stream>>>(h2, Bpout, combo2, bout, nullptr, d_out);
}

// Round 11
// 1367.627 us; speedup vs baseline: 1.0551x; 1.0551x over previous
//
#include <hip/hip_runtime.h>
#include <hip/hip_bf16.h>

#define NUMC 2048

typedef short bf16x8 __attribute__((ext_vector_type(8)));
typedef float f32x4 __attribute__((ext_vector_type(4)));
typedef int i32x8 __attribute__((ext_vector_type(8)));

__device__ __forceinline__ unsigned short f2bf(float f) {
  unsigned int u = __float_as_uint(f);
  u = u + 0x7fffu + ((u >> 16) & 1u);
  return (unsigned short)(u >> 16);
}
__device__ __forceinline__ float bf2f(unsigned short s) {
  return __uint_as_float(((unsigned int)s) << 16);
}
__device__ __forceinline__ float sigm(float x) {
  return __fdividef(1.f, 1.f + __expf(-x));
}
__device__ __forceinline__ float tanh_(float x) {
  float ax = fabsf(x);
  float s = __expf(-2.f * ax);
  float ta = __fdividef(1.f - s, 1.f + s);
  return copysignf(ta, x);
}
__device__ __forceinline__ unsigned int pack2(unsigned short a, unsigned short b) {
  return (unsigned int)a | ((unsigned int)b << 16);
}
// async 16B/lane global->LDS (lds dest = wave-uniform base + lane*16)
__device__ __forceinline__ void gll16(const void* g, void* lds) {
  __builtin_amdgcn_global_load_lds(
      (const __attribute__((address_space(1))) unsigned int*)g,
      (__attribute__((address_space(3))) unsigned int*)lds, 16, 0, 0);
}

// ---- pack B into linear MFMA slabs: Bp[((ks*Ng + ng)*64 + l)*8 + j] =
//      bf16(W[(ng*16 + (l&15))*320 + ks*32 + (l>>4)*8 + j]);  ks=0..9 (K=320)
__global__ void k_pack_b(const float* __restrict__ W, unsigned short* __restrict__ Bp,
                         int Nmask, int logNg) {
  int e = blockIdx.x * 256 + threadIdx.x;  // N*320 total
  int j = e & 7;
  int l = (e >> 3) & 63;
  int ng = (e >> 9) & Nmask;
  int ks = e >> (9 + logNg);
  int n = ng * 16 + (l & 15);
  int k = ks * 32 + (l >> 4) * 8 + j;
  Bp[e] = f2bf(W[n * 320 + k]);
}

// ---- per-gate-row scale for fp8 quantization of W_hh
__global__ void k_rowmax(const float* __restrict__ Whh, float* __restrict__ fs) {
  int row = blockIdx.x;
  int l = threadIdx.x;  // 64
  float m = 0.f;
#pragma unroll
  for (int i = 0; i < 4; ++i) m = fmaxf(m, fabsf(Whh[row * 256 + i * 64 + l]));
#pragma unroll
  for (int off = 32; off > 0; off >>= 1) m = fmaxf(m, __shfl_xor(m, off));
  if (l == 0) fs[row] = (m > 0.f ? m : 1.f) * (1.f / 192.f);
}

// ---- pack W_hh into fp8 e4m3 fragments for mfma_scale 16x16x128:
// frag = ((w*2+nt)*4+g)*2+kt ; lane l holds 32 bytes: k = kt*128 + (l>>4)*32 + 0..31
__global__ void k_pack_whh_mx(const float* __restrict__ Whh, const float* __restrict__ fs,
                              long long* __restrict__ P) {
  int e = blockIdx.x * 256 + threadIdx.x;  // 8192 lane-slots
  int l = e & 63;
  int frag = e >> 6;
  int kt = frag & 1;
  int g = (frag >> 1) & 3;
  int nt = (frag >> 3) & 1;
  int w = frag >> 4;
  int gr = g * 256 + w * 32 + nt * 16 + (l & 15);
  int k0 = kt * 128 + (l >> 4) * 32;
  float inv = __fdividef(1.f, fs[gr]);
#pragma unroll
  for (int q = 0; q < 4; ++q) {
    unsigned long long v = 0;
#pragma unroll
    for (int jj = 0; jj < 4; ++jj) {
      float w0 = Whh[gr * 256 + k0 + q * 8 + 2 * jj] * inv;
      float w1 = Whh[gr * 256 + k0 + q * 8 + 2 * jj + 1] * inv;
      int pk = __builtin_amdgcn_cvt_pk_fp8_f32(w0, w1, 0, 0);
      v |= (unsigned long long)(unsigned)(pk & 0xffff) << (16 * jj);
    }
    P[(size_t)e * 4 + q] = (long long)v;
  }
}

// ---- theta = bf16(E[x]*Cct), C2 = bf16(Cct_shifted), packed combos
__global__ void k_theta(const int* __restrict__ q, const int* __restrict__ r,
                        const int* __restrict__ rg_, const int* __restrict__ sg_,
                        const int* __restrict__ pc_, const int* __restrict__ srg_,
                        const int* __restrict__ ssg_, const int* __restrict__ spc_,
                        const float* __restrict__ E, const float* __restrict__ Wc,
                        unsigned short* __restrict__ theta, unsigned short* __restrict__ C2,
                        int* __restrict__ combo, int* __restrict__ combo2) {
  int tid = threadIdx.x;
  int row = blockIdx.x * 8 + (tid >> 5);
  int u0 = (tid & 31) * 8;
  int x = q[row] + NUMC * r[row];
  int rg = rg_[row], sg = sg_[row], pc = pc_[row];
  int g1 = srg_[row], g2 = ssg_[row], g3 = spc_[row];
  const float* e = E + (size_t)x * 256 + u0;
  unsigned short tv[8], cv[8];
#pragma unroll
  for (int i = 0; i < 8; ++i) {
    const float* wr = Wc + (size_t)(u0 + i) * 64;
    float cct = wr[rg] + wr[16 + sg] + wr[32 + pc];
    float cc2 = wr[g1] + wr[16 + g2] + wr[32 + g3];
    tv[i] = f2bf(e[i] * cct);
    cv[i] = f2bf(cc2);
  }
  uint4 tvec = {pack2(tv[0], tv[1]), pack2(tv[2], tv[3]), pack2(tv[4], tv[5]), pack2(tv[6], tv[7])};
  uint4 cvec = {pack2(cv[0], cv[1]), pack2(cv[2], cv[3]), pack2(cv[4], cv[5]), pack2(cv[6], cv[7])};
  *(uint4*)(theta + (size_t)row * 256 + u0) = tvec;
  *(uint4*)(C2 + (size_t)row * 256 + u0) = cvec;
  if ((tid & 31) == 0) {
    combo[row] = (rg * 16 + sg) * 32 + pc;
    combo2[row] = (g1 * 16 + g2) * 32 + g3;
  }
}

__device__ __forceinline__ uint4 onehot8(int k0, int rg, int sg, int pc) {
  unsigned vv[8];
#pragma unroll
  for (int j = 0; j < 8; ++j) {
    int k = k0 + j;
    vv[j] = (k == rg || k == sg || k == pc) ? 0x3F80u : 0u;
  }
  uint4 rr;
  rr.x = vv[0] | (vv[1] << 16);
  rr.y = vv[2] | (vv[3] << 16);
  rr.z = vv[4] | (vv[5] << 16);
  rr.w = vv[6] | (vv[7] << 16);
  return rr;
}

// ---- 128x128xK=320 bf16 MFMA GEMM, double-buffered, counted-vmcnt pipeline (T3+T4):
// STAGE(ks+1) issued early; barrier #1 = s_waitcnt vmcnt(N)+s_barrier waits ONLY
// stage(ks); barrier #2 = lgkmcnt(0)+s_barrier (buffer-reuse, no vm drain).
// MODE 0: xg = [A|ct]*B^T + b_ih + b_hh -> bf16.  MODE 1: y = sigmoid(..+b_out) -> f32
template <int NTOT, int MODE, int LOGGX>
__global__ __launch_bounds__(256) void k_gemm(
    const unsigned short* __restrict__ A, const unsigned short* __restrict__ Bp,
    const int* __restrict__ combo, const float* __restrict__ bias1,
    const float* __restrict__ bias2, void* __restrict__ Out) {
  __shared__ __align__(16) unsigned short As[2][4096];  // 2 x 8 slabs [lane64][8]
  __shared__ __align__(16) unsigned short Bs[2][4096];
  const int tid = threadIdx.x;
  const int w = tid >> 6, l = tid & 63;
  const int wm = w >> 1, wn = w & 1;
  constexpr int NG = NTOT / 16;

  int id = blockIdx.y * (1 << LOGGX) + blockIdx.x;
  int Nbase = ((id >> 3) & ((1 << LOGGX) - 1)) * 128;
  int Mbase = ((((id >> (3 + LOGGX)) << 3) | (id & 7))) * 128;

  f32x4 acc[4][4];
#pragma unroll
  for (int i = 0; i < 4; ++i)
#pragma unroll
    for (int j = 0; j < 4; ++j) acc[i][j] = (f32x4){0.f, 0.f, 0.f, 0.f};

  // staging addresses: wave w owns slabs 2w, 2w+1 of both A and B
  const unsigned short* gA = A + (size_t)(Mbase + (2 * w) * 16 + (l & 15)) * 256 + (l >> 4) * 8;
  const unsigned short* gB = Bp + ((size_t)(Nbase / 16 + 2 * w) * 64 + l) * 8;

  // one-hot synth params (K tail)
  const int arow = tid >> 1;
  const int agp = (tid & 1) * 2;
  const int a_ch = arow >> 4;
  const int a_ls0 = (arow & 15) | (agp << 4);
  const int a_ls1 = (arow & 15) | ((agp + 1) << 4);
  const int cmb = combo[Mbase + arow];
  const int rg = cmb >> 9, sg = 16 + ((cmb >> 5) & 15), pc = 32 + (cmb & 31);

  // STAGE K-step ks into buffer nb.  vmem loads/wave: ks<8 -> 4, ks in {8,9} -> 2.
  auto STAGE = [&](int ks, int nb) {
    if (ks < 8) {
      gll16(gA + ks * 32, &As[nb][(2 * w) * 512]);
      gll16(gA + ks * 32 + 16 * 256, &As[nb][(2 * w + 1) * 512]);
    } else {
      int k0 = (ks - 8) * 32 + agp * 8;
      uint4 av0 = onehot8(k0, rg, sg, pc);
      uint4 av1 = onehot8(k0 + 8, rg, sg, pc);
      *(uint4*)&As[nb][(a_ch * 64 + a_ls0) * 8] = av0;
      *(uint4*)&As[nb][(a_ch * 64 + a_ls1) * 8] = av1;
    }
    gll16(gB + (size_t)ks * NG * 512, &Bs[nb][(2 * w) * 512]);
    gll16(gB + (size_t)ks * NG * 512 + 64 * 8, &Bs[nb][(2 * w + 1) * 512]);
  };

  STAGE(0, 0);

#pragma unroll
  for (int ks = 0; ks < 10; ++ks) {
    const int b = ks & 1;
    if (ks < 9) STAGE(ks + 1, b ^ 1);  // issue-early; lands during MFMA + next iter
    // barrier #1: wait ONLY stage(ks)'s loads (outstanding: this stage's newer ones stay)
    if (ks < 7)
      asm volatile("s_waitcnt vmcnt(4)\ns_barrier" ::: "memory");
    else if (ks < 9)
      asm volatile("s_waitcnt vmcnt(2)\ns_barrier" ::: "memory");
    else
      asm volatile("s_waitcnt vmcnt(0)\ns_barrier" ::: "memory");
    bf16x8 bfr[4];
#pragma unroll
    for (int ni = 0; ni < 4; ++ni)
      bfr[ni] = *(const bf16x8*)&Bs[b][((wn * 4 + ni) * 64 + l) * 8];
#pragma unroll
    for (int mi = 0; mi < 4; ++mi) {
      bf16x8 af = *(const bf16x8*)&As[b][((wm * 4 + mi) * 64 + l) * 8];
#pragma unroll
      for (int ni = 0; ni < 4; ++ni)
        acc[mi][ni] = __builtin_amdgcn_mfma_f32_16x16x32_bf16(af, bfr[ni], acc[mi][ni], 0, 0, 0);
    }
    // barrier #2: all waves done reading buf b (LDS-only wait; vm stays in flight)
    asm volatile("s_waitcnt lgkmcnt(0)\ns_barrier" ::: "memory");
  }

  int lh = l >> 4, col = l & 15;
  float badd[4];
#pragma unroll
  for (int ni = 0; ni < 4; ++ni) {
    int gcol = Nbase + wn * 64 + ni * 16 + col;
    badd[ni] = bias1[gcol] + (MODE == 0 ? bias2[gcol] : 0.f);
  }
#pragma unroll
  for (int mi = 0; mi < 4; ++mi) {
    int grow0 = Mbase + wm * 64 + mi * 16 + lh * 4;
#pragma unroll
    for (int rr = 0; rr < 4; ++rr) {
      int grow = grow0 + rr;
#pragma unroll
      for (int ni = 0; ni < 4; ++ni) {
        int gcol = Nbase + wn * 64 + ni * 16 + col;
        float v = acc[mi][ni][rr] + badd[ni];
        if (MODE == 0) {
          ((unsigned short*)Out)[(size_t)grow * NTOT + gcol] = f2bf(v);
        } else {
          ((float*)Out)[(size_t)grow * NTOT + gcol] = sigm(v);
        }
      }
    }
  }
}

// ---- LSTM: 256 independent blocks x 1 batch row; all 1024 gates per block.
// W_hh fp8 in VGPRs, mfma_scale 16x16x128; running-sum acc (no reset); gate-spread
// epilogue (2 gates/lane).  NEW: per-step barrier is lgkmcnt-only (h2 stores and
// xg/C2 prefetch loads stay in flight across barriers); t-loop unrolled by 2 with
// named A/B prefetch regs issued post-consumption -> ~2 steps of load slack.
__global__ __launch_bounds__(512, 1) void k_lstm(
    const unsigned short* __restrict__ xg, const unsigned short* __restrict__ C2,
    const long long* __restrict__ Wq, const float* __restrict__ fs,
    unsigned short* __restrict__ h2) {
  __shared__ __align__(16) char hq[2][4224];
  const int tid = threadIdx.x;
  const int w = tid >> 6, l = tid & 63;
  const int col = l & 15;
  const int half = (l >> 4) & 1;  // 0: i,f lanes   1: g,o lanes
  const int ntsel = l >> 5;
  const int blk = blockIdx.x;  // 256 blocks

  i32x8 wreg[2][4][2];
#pragma unroll
  for (int nt = 0; nt < 2; ++nt)
#pragma unroll
    for (int g = 0; g < 4; ++g)
#pragma unroll
      for (int kt = 0; kt < 2; ++kt)
        wreg[nt][g][kt] =
            ((const i32x8*)Wq)[(((w * 2 + nt) * 4 + g) * 2 + kt) * 64 + l];

  const int u = w * 32 + ntsel * 16 + col;
  const float fsa = fs[(half * 2 + 0) * 256 + u];
  const float fsb = fs[(half * 2 + 1) * 256 + u];
  const float AA = half ? 2.f : 1.f;
  const float BB = half ? -1.f : 0.f;
  const float SS = half ? 2.f : 1.f;

  {
    uint4 zz = {0u, 0u, 0u, 0u};
    ((uint4*)hq)[tid] = zz;
    if (tid < 16) ((uint4*)hq)[512 + tid] = zz;
  }

  const unsigned bg = (unsigned)blk;
  const unsigned xg0 = (bg << 19) + (unsigned)((half * 2) * 256 + u);
  const unsigned c0 = (bg << 17) + (unsigned)u;

  // preload t=0 (A regs) and t=1 (B regs)
  unsigned short xaA = xg[xg0], xbA = xg[xg0 + 256];
  unsigned short ccA = C2[c0];
  unsigned short xaB = xg[xg0 + 1024], xbB = xg[xg0 + 1280];
  unsigned short ccB = C2[c0 + 256];
  unsigned xbE = xg0 + 2048;  // xg issue addr for even phase (t2+2)
  unsigned cbh = c0;          // h2 store addr for even phase (t2)

  __syncthreads();

  float cst = 0.f, SoldA = 0.f, SoldB = 0.f;
  f32x4 acc[2][4];
#pragma unroll
  for (int nt = 0; nt < 2; ++nt)
#pragma unroll
    for (int g = 0; g < 4; ++g) acc[nt][g] = (f32x4){0.f, 0.f, 0.f, 0.f};

  // one LSTM step: MFMA on hq[PB], epilogue consuming (XA,XB,CC), write hq[PB^1],
  // then issue prefetch loads (t+2) into the just-freed regs, then lgkm-only barrier.
  auto PHASE = [&](int PB, unsigned short& XA, unsigned short& XB, unsigned short& CC,
                   unsigned h2addr, unsigned xissA, unsigned xissB, unsigned ciss) {
#pragma unroll
    for (int kt = 0; kt < 2; ++kt) {
      int ab = col * 264 + kt * 128 + (l >> 4) * 32;
      uint4 a0 = *(const uint4*)&hq[PB][ab];
      uint4 a1 = *(const uint4*)&hq[PB][ab + 16];
      i32x8 av;
      av[0] = (int)a0.x; av[1] = (int)a0.y; av[2] = (int)a0.z; av[3] = (int)a0.w;
      av[4] = (int)a1.x; av[5] = (int)a1.y; av[6] = (int)a1.z; av[7] = (int)a1.w;
#pragma unroll
      for (int nt = 0; nt < 2; ++nt)
#pragma unroll
        for (int g = 0; g < 4; ++g)
          acc[nt][g] = __builtin_amdgcn_mfma_scale_f32_16x16x128_f8f6f4(
              av, wreg[nt][g][kt], acc[nt][g], 0, 0, 0, 0x7F7F7F7F, 0, 0x7F7F7F7F);
    }
    float m0 = __uint_as_float(
        __builtin_amdgcn_permlane32_swap(__float_as_uint(acc[0][0][0]),
                                         __float_as_uint(acc[1][0][0]), false, false)[0]);
    float m1 = __uint_as_float(
        __builtin_amdgcn_permlane32_swap(__float_as_uint(acc[0][1][0]),
                                         __float_as_uint(acc[1][1][0]), false, false)[0]);
    float m2 = __uint_as_float(
        __builtin_amdgcn_permlane32_swap(__float_as_uint(acc[0][2][0]),
                                         __float_as_uint(acc[1][2][0]), false, false)[0]);
    float m3 = __uint_as_float(
        __builtin_amdgcn_permlane32_swap(__float_as_uint(acc[0][3][0]),
                                         __float_as_uint(acc[1][3][0]), false, false)[0]);
    float mm2 = __shfl_xor(m2, 16);
    float mm3 = __shfl_xor(m3, 16);
    float a_ = half ? mm2 : m0;
    float b_ = half ? mm3 : m1;
    float pa = a_ - SoldA;
    SoldA = a_;
    float pb_ = b_ - SoldB;
    SoldB = b_;
    float va = pa * fsa + bf2f(XA);
    float vb = pb_ * fsb + bf2f(XB);
    float ra = AA * __fdividef(1.f, 1.f + __expf(-SS * va)) + BB;
    float rb = sigm(vb);
    float si = __shfl_xor(ra, 16);
    float sf = __shfl_xor(rb, 16);
    float cv = sf * cst + si * ra;
    cst = cv;
    float th = tanh_(cv);
    float hv = rb * th;
    if (half) {
      h2[h2addr] = f2bf(hv * bf2f(CC));
      int pk = __builtin_amdgcn_cvt_pk_fp8_f32(hv, hv, 0, 0);
      hq[PB ^ 1][u] = (char)(pk & 255);
    }
    // prefetch t+2 into freed regs (never drained at the barrier below)
    XA = xg[xissA];
    XB = xg[xissB];
    CC = C2[ciss];
    asm volatile("s_waitcnt lgkmcnt(0)\ns_barrier" ::: "memory");
  };

#pragma unroll 1
  for (int t2 = 0; t2 < 512; t2 += 2) {
    PHASE(0, xaA, xbA, ccA, cbh, xbE, xbE + 256, cbh + 512);
    PHASE(1, xaB, xbB, ccB, cbh + 256, xbE + 1024, xbE + 1280, cbh + 768);
    xbE += 2048;
    cbh += 512;
  }
}

extern "C" void kernel_launch(void* const* d_in, const int* in_sizes, int n_in,
                              void* d_out, int out_size, void* d_ws, size_t ws_size,
                              hipStream_t stream) {
  const int* q = (const int*)d_in[0];
  const int* r = (const int*)d_in[1];
  const int* rg = (const int*)d_in[2];
  const int* sg = (const int*)d_in[3];
  const int* pc = (const int*)d_in[4];
  const int* srg = (const int*)d_in[5];
  const int* ssg = (const int*)d_in[6];
  const int* spc = (const int*)d_in[7];
  const float* E = (const float*)d_in[8];
  const float* Wc = (const float*)d_in[9];
  const float* Wih = (const float*)d_in[10];
  const float* Whh = (const float*)d_in[11];
  const float* bih = (const float*)d_in[12];
  const float* bhh = (const float*)d_in[13];
  const float* Wout = (const float*)d_in[14];
  const float* bout = (const float*)d_in[15];

  char* ws = (char*)d_ws;
  unsigned short* h2 = (unsigned short*)(ws);                // 64 MB
  unsigned short* Bpih = (unsigned short*)(ws + 67108864);   // 640 KB
  unsigned short* Bpout = (unsigned short*)(ws + 67764224);  // 1.25 MB
  long long* Wq = (long long*)(ws + 69074944);               // 256 KB
  float* fs = (float*)(ws + 69337088);                       // 4 KB
  int* combo = (int*)(ws + 69341184);                        // 512 KB
  int* combo2 = (int*)(ws + 69865472);                       // 512 KB (end 70389760)

  char* dout = (char*)d_out;
  unsigned short* xg = (unsigned short*)dout;                    // 256 MB (dead until final GEMM)
  unsigned short* theta = (unsigned short*)(dout + 268435456);   // 64 MB
  unsigned short* C2 = (unsigned short*)(dout + 335544320);      // 64 MB

  k_rowmax<<<1024, 64, 0, stream>>>(Whh, fs);
  k_pack_whh_mx<<<32, 256, 0, stream>>>(Whh, fs, Wq);
  k_pack_b<<<1280, 256, 0, stream>>>(Wih, Bpih, 63, 6);
  k_pack_b<<<2560, 256, 0, stream>>>(Wout, Bpout, 127, 7);
  k_theta<<<16384, 256, 0, stream>>>(q, r, rg, sg, pc, srg, ssg, spc, E, Wc, theta, C2, combo, combo2);
  k_gemm<1024, 0, 3><<<dim3(8, 1024), 256, 0, stream>>>(theta, Bpih, combo, bih, bhh, (void*)xg);
  k_lstm<<<256, 512, 0, stream>>>(xg, C2, Wq, fs, h2);
  k_gemm<2048, 1, 4><<<dim3(16, 1024), 256, 0, stream>>>(h2, Bpout, combo2, bout, nullptr, d_out);
}

// Round 12
// 1083.310 us; speedup vs baseline: 1.3321x; 1.2625x over previous
//
#include <hip/hip_runtime.h>
#include <hip/hip_bf16.h>

#define NUMC 2048

typedef short bf16x8 __attribute__((ext_vector_type(8)));
typedef float f32x4 __attribute__((ext_vector_type(4)));
typedef int i32x8 __attribute__((ext_vector_type(8)));

__device__ __forceinline__ unsigned short f2bf(float f) {
  unsigned int u = __float_as_uint(f);
  u = u + 0x7fffu + ((u >> 16) & 1u);
  return (unsigned short)(u >> 16);
}
__device__ __forceinline__ float bf2f(unsigned short s) {
  return __uint_as_float(((unsigned int)s) << 16);
}
__device__ __forceinline__ float sigm(float x) {
  return __fdividef(1.f, 1.f + __expf(-x));
}
__device__ __forceinline__ float tanh_(float x) {
  float ax = fabsf(x);
  float s = __expf(-2.f * ax);
  float ta = __fdividef(1.f - s, 1.f + s);
  return copysignf(ta, x);
}
__device__ __forceinline__ unsigned int pack2(unsigned short a, unsigned short b) {
  return (unsigned int)a | ((unsigned int)b << 16);
}
// async 16B/lane global->LDS (lds dest = wave-uniform base + lane*16)
__device__ __forceinline__ void gll16(const void* g, void* lds) {
  __builtin_amdgcn_global_load_lds(
      (const __attribute__((address_space(1))) unsigned int*)g,
      (__attribute__((address_space(3))) unsigned int*)lds, 16, 0, 0);
}

// ---- pack B into linear MFMA slabs: Bp[((ks*Ng + ng)*64 + l)*8 + j] =
//      bf16(W[(ng*16 + (l&15))*320 + ks*32 + (l>>4)*8 + j]);  ks=0..9 (K=320)
__global__ void k_pack_b(const float* __restrict__ W, unsigned short* __restrict__ Bp,
                         int Nmask, int logNg) {
  int e = blockIdx.x * 256 + threadIdx.x;  // N*320 total
  int j = e & 7;
  int l = (e >> 3) & 63;
  int ng = (e >> 9) & Nmask;
  int ks = e >> (9 + logNg);
  int n = ng * 16 + (l & 15);
  int k = ks * 32 + (l >> 4) * 8 + j;
  Bp[e] = f2bf(W[n * 320 + k]);
}

// ---- per-gate-row scale for fp8 quantization of W_hh
__global__ void k_rowmax(const float* __restrict__ Whh, float* __restrict__ fs) {
  int row = blockIdx.x;
  int l = threadIdx.x;  // 64
  float m = 0.f;
#pragma unroll
  for (int i = 0; i < 4; ++i) m = fmaxf(m, fabsf(Whh[row * 256 + i * 64 + l]));
#pragma unroll
  for (int off = 32; off > 0; off >>= 1) m = fmaxf(m, __shfl_xor(m, off));
  if (l == 0) fs[row] = (m > 0.f ? m : 1.f) * (1.f / 192.f);
}

// ---- transpose Wc: WcT[t][c] = Wc[c][t]   (64 x 256, L2-resident)
__global__ void k_wct(const float* __restrict__ Wc, float* __restrict__ WcT) {
  int e = blockIdx.x * 256 + threadIdx.x;  // 16384
  int t = e >> 8, c = e & 255;
  WcT[t * 256 + c] = Wc[c * 64 + t];
}

// ---- pack W_hh into fp8 e4m3 fragments for mfma_scale 16x16x128:
// frag = ((w*2+nt)*4+g)*2+kt ; lane l holds 32 bytes: k = kt*128 + (l>>4)*32 + 0..31
__global__ void k_pack_whh_mx(const float* __restrict__ Whh, const float* __restrict__ fs,
                              long long* __restrict__ P) {
  int e = blockIdx.x * 256 + threadIdx.x;  // 8192 lane-slots
  int l = e & 63;
  int frag = e >> 6;
  int kt = frag & 1;
  int g = (frag >> 1) & 3;
  int nt = (frag >> 3) & 1;
  int w = frag >> 4;
  int gr = g * 256 + w * 32 + nt * 16 + (l & 15);
  int k0 = kt * 128 + (l >> 4) * 32;
  float inv = __fdividef(1.f, fs[gr]);
#pragma unroll
  for (int q = 0; q < 4; ++q) {
    unsigned long long v = 0;
#pragma unroll
    for (int jj = 0; jj < 4; ++jj) {
      float w0 = Whh[gr * 256 + k0 + q * 8 + 2 * jj] * inv;
      float w1 = Whh[gr * 256 + k0 + q * 8 + 2 * jj + 1] * inv;
      int pk = __builtin_amdgcn_cvt_pk_fp8_f32(w0, w1, 0, 0);
      v |= (unsigned long long)(unsigned)(pk & 0xffff) << (16 * jj);
    }
    P[(size_t)e * 4 + q] = (long long)v;
  }
}

// ---- theta = bf16(E[x]*Cct), C2 = bf16(Cct_shifted), packed combos.
// Uses WcT (transposed) so every gather is a contiguous float4 pair.
__global__ void k_theta(const int* __restrict__ q, const int* __restrict__ r,
                        const int* __restrict__ rg_, const int* __restrict__ sg_,
                        const int* __restrict__ pc_, const int* __restrict__ srg_,
                        const int* __restrict__ ssg_, const int* __restrict__ spc_,
                        const float* __restrict__ E, const float* __restrict__ WcT,
                        unsigned short* __restrict__ theta, unsigned short* __restrict__ C2,
                        int* __restrict__ combo, int* __restrict__ combo2) {
  int tid = threadIdx.x;
  int row = blockIdx.x * 8 + (tid >> 5);
  int u0 = (tid & 31) * 8;
  int x = q[row] + NUMC * r[row];
  int rg = rg_[row], sg = sg_[row], pc = pc_[row];
  int g1 = srg_[row], g2 = ssg_[row], g3 = spc_[row];
  const float4* e4 = (const float4*)(E + (size_t)x * 256 + u0);
  float4 ea = e4[0], eb = e4[1];
  auto ld = [&](int rr, float4& lo, float4& hi) {
    const float4* p = (const float4*)(WcT + rr * 256 + u0);
    lo = p[0];
    hi = p[1];
  };
  float4 a0, a1, b0, b1, c0, c1, d0, d1, f0, f1, h0, h1;
  ld(rg, a0, a1);
  ld(16 + sg, b0, b1);
  ld(32 + pc, c0, c1);
  ld(g1, d0, d1);
  ld(16 + g2, f0, f1);
  ld(32 + g3, h0, h1);
  float ct[8], c2[8], ev[8];
  ct[0] = a0.x + b0.x + c0.x; ct[1] = a0.y + b0.y + c0.y;
  ct[2] = a0.z + b0.z + c0.z; ct[3] = a0.w + b0.w + c0.w;
  ct[4] = a1.x + b1.x + c1.x; ct[5] = a1.y + b1.y + c1.y;
  ct[6] = a1.z + b1.z + c1.z; ct[7] = a1.w + b1.w + c1.w;
  c2[0] = d0.x + f0.x + h0.x; c2[1] = d0.y + f0.y + h0.y;
  c2[2] = d0.z + f0.z + h0.z; c2[3] = d0.w + f0.w + h0.w;
  c2[4] = d1.x + f1.x + h1.x; c2[5] = d1.y + f1.y + h1.y;
  c2[6] = d1.z + f1.z + h1.z; c2[7] = d1.w + f1.w + h1.w;
  ev[0] = ea.x; ev[1] = ea.y; ev[2] = ea.z; ev[3] = ea.w;
  ev[4] = eb.x; ev[5] = eb.y; ev[6] = eb.z; ev[7] = eb.w;
  unsigned short tv[8], cv[8];
#pragma unroll
  for (int i = 0; i < 8; ++i) {
    tv[i] = f2bf(ev[i] * ct[i]);
    cv[i] = f2bf(c2[i]);
  }
  uint4 tvec = {pack2(tv[0], tv[1]), pack2(tv[2], tv[3]), pack2(tv[4], tv[5]), pack2(tv[6], tv[7])};
  uint4 cvec = {pack2(cv[0], cv[1]), pack2(cv[2], cv[3]), pack2(cv[4], cv[5]), pack2(cv[6], cv[7])};
  *(uint4*)(theta + (size_t)row * 256 + u0) = tvec;
  *(uint4*)(C2 + (size_t)row * 256 + u0) = cvec;
  if ((tid & 31) == 0) {
    combo[row] = (rg * 16 + sg) * 32 + pc;
    combo2[row] = (g1 * 16 + g2) * 32 + g3;
  }
}

__device__ __forceinline__ uint4 onehot8(int k0, int rg, int sg, int pc) {
  unsigned vv[8];
#pragma unroll
  for (int j = 0; j < 8; ++j) {
    int k = k0 + j;
    vv[j] = (k == rg || k == sg || k == pc) ? 0x3F80u : 0u;
  }
  uint4 rr;
  rr.x = vv[0] | (vv[1] << 16);
  rr.y = vv[2] | (vv[3] << 16);
  rr.z = vv[4] | (vv[5] << 16);
  rr.w = vv[6] | (vv[7] << 16);
  return rr;
}

// ---- 128x128xK=320 bf16 MFMA GEMM, TRIPLE-buffered counted-vmcnt pipeline:
// STAGE(ks+2) issued early -> every load has ~2 MFMA phases to land.
// barrier #1 = vmcnt(N)+s_barrier waits ONLY stage(ks); N = loads of stages ks+1,ks+2
// (8,8,8,8,8,8,6,4,2,0). barrier #2 = lgkmcnt(0)+s_barrier (buffer reuse, no vm drain).
// MODE 0: xg = [A|ct]*B^T + b_ih + b_hh -> bf16.  MODE 1: y = sigmoid(..+b_out) -> f32
template <int NTOT, int MODE, int LOGGX>
__global__ __launch_bounds__(256) void k_gemm(
    const unsigned short* __restrict__ A, const unsigned short* __restrict__ Bp,
    const int* __restrict__ combo, const float* __restrict__ bias1,
    const float* __restrict__ bias2, void* __restrict__ Out) {
  __shared__ __align__(16) unsigned short As[3][4096];
  __shared__ __align__(16) unsigned short Bs[3][4096];
  const int tid = threadIdx.x;
  const int w = tid >> 6, l = tid & 63;
  const int wm = w >> 1, wn = w & 1;
  constexpr int NG = NTOT / 16;

  int id = blockIdx.y * (1 << LOGGX) + blockIdx.x;
  int Nbase = ((id >> 3) & ((1 << LOGGX) - 1)) * 128;
  int Mbase = ((((id >> (3 + LOGGX)) << 3) | (id & 7))) * 128;

  f32x4 acc[4][4];
#pragma unroll
  for (int i = 0; i < 4; ++i)
#pragma unroll
    for (int j = 0; j < 4; ++j) acc[i][j] = (f32x4){0.f, 0.f, 0.f, 0.f};

  // staging addresses: wave w owns slabs 2w, 2w+1 of both A and B
  const unsigned short* gA = A + (size_t)(Mbase + (2 * w) * 16 + (l & 15)) * 256 + (l >> 4) * 8;
  const unsigned short* gB = Bp + ((size_t)(Nbase / 16 + 2 * w) * 64 + l) * 8;

  // one-hot synth params (K tail)
  const int arow = tid >> 1;
  const int agp = (tid & 1) * 2;
  const int a_ch = arow >> 4;
  const int a_ls0 = (arow & 15) | (agp << 4);
  const int a_ls1 = (arow & 15) | ((agp + 1) << 4);
  const int cmb = combo[Mbase + arow];
  const int rg = cmb >> 9, sg = 16 + ((cmb >> 5) & 15), pc = 32 + (cmb & 31);

  // STAGE K-step ks into buffer nb.  vmem loads/wave: ks<8 -> 4, ks in {8,9} -> 2.
  auto STAGE = [&](int ks, int nb) {
    if (ks < 8) {
      gll16(gA + ks * 32, &As[nb][(2 * w) * 512]);
      gll16(gA + ks * 32 + 16 * 256, &As[nb][(2 * w + 1) * 512]);
    } else {
      int k0 = (ks - 8) * 32 + agp * 8;
      uint4 av0 = onehot8(k0, rg, sg, pc);
      uint4 av1 = onehot8(k0 + 8, rg, sg, pc);
      *(uint4*)&As[nb][(a_ch * 64 + a_ls0) * 8] = av0;
      *(uint4*)&As[nb][(a_ch * 64 + a_ls1) * 8] = av1;
    }
    gll16(gB + (size_t)ks * NG * 512, &Bs[nb][(2 * w) * 512]);
    gll16(gB + (size_t)ks * NG * 512 + 64 * 8, &Bs[nb][(2 * w + 1) * 512]);
  };

  STAGE(0, 0);
  STAGE(1, 1);

#pragma unroll
  for (int ks = 0; ks < 10; ++ks) {
    const int b = ks % 3;
    if (ks < 8) STAGE(ks + 2, (ks + 2) % 3);  // depth-2 prefetch
    // barrier #1: wait only stage(ks)'s loads (stages ks+1, ks+2 stay in flight)
    if (ks <= 5)
      asm volatile("s_waitcnt vmcnt(8)\ns_barrier" ::: "memory");
    else if (ks == 6)
      asm volatile("s_waitcnt vmcnt(6)\ns_barrier" ::: "memory");
    else if (ks == 7)
      asm volatile("s_waitcnt vmcnt(4)\ns_barrier" ::: "memory");
    else if (ks == 8)
      asm volatile("s_waitcnt vmcnt(2)\ns_barrier" ::: "memory");
    else
      asm volatile("s_waitcnt vmcnt(0)\ns_barrier" ::: "memory");
    bf16x8 bfr[4];
#pragma unroll
    for (int ni = 0; ni < 4; ++ni)
      bfr[ni] = *(const bf16x8*)&Bs[b][((wn * 4 + ni) * 64 + l) * 8];
#pragma unroll
    for (int mi = 0; mi < 4; ++mi) {
      bf16x8 af = *(const bf16x8*)&As[b][((wm * 4 + mi) * 64 + l) * 8];
#pragma unroll
      for (int ni = 0; ni < 4; ++ni)
        acc[mi][ni] = __builtin_amdgcn_mfma_f32_16x16x32_bf16(af, bfr[ni], acc[mi][ni], 0, 0, 0);
    }
    // barrier #2: all waves done reading buf b (LDS-only wait; vm stays in flight)
    asm volatile("s_waitcnt lgkmcnt(0)\ns_barrier" ::: "memory");
  }

  int lh = l >> 4, col = l & 15;
  float badd[4];
#pragma unroll
  for (int ni = 0; ni < 4; ++ni) {
    int gcol = Nbase + wn * 64 + ni * 16 + col;
    badd[ni] = bias1[gcol] + (MODE == 0 ? bias2[gcol] : 0.f);
  }
#pragma unroll
  for (int mi = 0; mi < 4; ++mi) {
    int grow0 = Mbase + wm * 64 + mi * 16 + lh * 4;
#pragma unroll
    for (int rr = 0; rr < 4; ++rr) {
      int grow = grow0 + rr;
#pragma unroll
      for (int ni = 0; ni < 4; ++ni) {
        int gcol = Nbase + wn * 64 + ni * 16 + col;
        float v = acc[mi][ni][rr] + badd[ni];
        if (MODE == 0) {
          ((unsigned short*)Out)[(size_t)grow * NTOT + gcol] = f2bf(v);
        } else {
          ((float*)Out)[(size_t)grow * NTOT + gcol] = sigm(v);
        }
      }
    }
  }
}

// ---- LSTM: 256 independent blocks x 1 batch row; all 1024 gates per block.
// W_hh fp8 in VGPRs, mfma_scale 16x16x128; running-sum acc (no reset); gate-spread
// epilogue (2 gates/lane); lgkm-only barriers; 2-step unrolled named prefetch regs.
__global__ __launch_bounds__(512, 1) void k_lstm(
    const unsigned short* __restrict__ xg, const unsigned short* __restrict__ C2,
    const long long* __restrict__ Wq, const float* __restrict__ fs,
    unsigned short* __restrict__ h2) {
  __shared__ __align__(16) char hq[2][4224];
  const int tid = threadIdx.x;
  const int w = tid >> 6, l = tid & 63;
  const int col = l & 15;
  const int half = (l >> 4) & 1;  // 0: i,f lanes   1: g,o lanes
  const int ntsel = l >> 5;
  const int blk = blockIdx.x;  // 256 blocks

  i32x8 wreg[2][4][2];
#pragma unroll
  for (int nt = 0; nt < 2; ++nt)
#pragma unroll
    for (int g = 0; g < 4; ++g)
#pragma unroll
      for (int kt = 0; kt < 2; ++kt)
        wreg[nt][g][kt] =
            ((const i32x8*)Wq)[(((w * 2 + nt) * 4 + g) * 2 + kt) * 64 + l];

  const int u = w * 32 + ntsel * 16 + col;
  const float fsa = fs[(half * 2 + 0) * 256 + u];
  const float fsb = fs[(half * 2 + 1) * 256 + u];
  const float AA = half ? 2.f : 1.f;
  const float BB = half ? -1.f : 0.f;
  const float SS = half ? 2.f : 1.f;

  {
    uint4 zz = {0u, 0u, 0u, 0u};
    ((uint4*)hq)[tid] = zz;
    if (tid < 16) ((uint4*)hq)[512 + tid] = zz;
  }

  const unsigned bg = (unsigned)blk;
  const unsigned xg0 = (bg << 19) + (unsigned)((half * 2) * 256 + u);
  const unsigned c0 = (bg << 17) + (unsigned)u;

  // preload t=0 (A regs) and t=1 (B regs)
  unsigned short xaA = xg[xg0], xbA = xg[xg0 + 256];
  unsigned short ccA = C2[c0];
  unsigned short xaB = xg[xg0 + 1024], xbB = xg[xg0 + 1280];
  unsigned short ccB = C2[c0 + 256];
  unsigned xbE = xg0 + 2048;  // xg issue addr for even phase (t2+2)
  unsigned cbh = c0;          // h2 store addr for even phase (t2)

  __syncthreads();

  float cst = 0.f, SoldA = 0.f, SoldB = 0.f;
  f32x4 acc[2][4];
#pragma unroll
  for (int nt = 0; nt < 2; ++nt)
#pragma unroll
    for (int g = 0; g < 4; ++g) acc[nt][g] = (f32x4){0.f, 0.f, 0.f, 0.f};

  auto PHASE = [&](int PB, unsigned short& XA, unsigned short& XB, unsigned short& CC,
                   unsigned h2addr, unsigned xissA, unsigned xissB, unsigned ciss) {
#pragma unroll
    for (int kt = 0; kt < 2; ++kt) {
      int ab = col * 264 + kt * 128 + (l >> 4) * 32;
      uint4 a0 = *(const uint4*)&hq[PB][ab];
      uint4 a1 = *(const uint4*)&hq[PB][ab + 16];
      i32x8 av;
      av[0] = (int)a0.x; av[1] = (int)a0.y; av[2] = (int)a0.z; av[3] = (int)a0.w;
      av[4] = (int)a1.x; av[5] = (int)a1.y; av[6] = (int)a1.z; av[7] = (int)a1.w;
#pragma unroll
      for (int nt = 0; nt < 2; ++nt)
#pragma unroll
        for (int g = 0; g < 4; ++g)
          acc[nt][g] = __builtin_amdgcn_mfma_scale_f32_16x16x128_f8f6f4(
              av, wreg[nt][g][kt], acc[nt][g], 0, 0, 0, 0x7F7F7F7F, 0, 0x7F7F7F7F);
    }
    float m0 = __uint_as_float(
        __builtin_amdgcn_permlane32_swap(__float_as_uint(acc[0][0][0]),
                                         __float_as_uint(acc[1][0][0]), false, false)[0]);
    float m1 = __uint_as_float(
        __builtin_amdgcn_permlane32_swap(__float_as_uint(acc[0][1][0]),
                                         __float_as_uint(acc[1][1][0]), false, false)[0]);
    float m2 = __uint_as_float(
        __builtin_amdgcn_permlane32_swap(__float_as_uint(acc[0][2][0]),
                                         __float_as_uint(acc[1][2][0]), false, false)[0]);
    float m3 = __uint_as_float(
        __builtin_amdgcn_permlane32_swap(__float_as_uint(acc[0][3][0]),
                                         __float_as_uint(acc[1][3][0]), false, false)[0]);
    float mm2 = __shfl_xor(m2, 16);
    float mm3 = __shfl_xor(m3, 16);
    float a_ = half ? mm2 : m0;
    float b_ = half ? mm3 : m1;
    float pa = a_ - SoldA;
    SoldA = a_;
    float pb_ = b_ - SoldB;
    SoldB = b_;
    float va = pa * fsa + bf2f(XA);
    float vb = pb_ * fsb + bf2f(XB);
    float ra = AA * __fdividef(1.f, 1.f + __expf(-SS * va)) + BB;
    float rb = sigm(vb);
    float si = __shfl_xor(ra, 16);
    float sf = __shfl_xor(rb, 16);
    float cv = sf * cst + si * ra;
    cst = cv;
    float th = tanh_(cv);
    float hv = rb * th;
    if (half) {
      // LDS write first (its completion gates the barrier), then global store
      int pk = __builtin_amdgcn_cvt_pk_fp8_f32(hv, hv, 0, 0);
      hq[PB ^ 1][u] = (char)(pk & 255);
      h2[h2addr] = f2bf(hv * bf2f(CC));
    }
    // prefetch t+2 into freed regs (never drained at the barrier below)
    XA = xg[xissA];
    XB = xg[xissB];
    CC = C2[ciss];
    asm volatile("s_waitcnt lgkmcnt(0)\ns_barrier" ::: "memory");
  };

#pragma unroll 1
  for (int t2 = 0; t2 < 512; t2 += 2) {
    PHASE(0, xaA, xbA, ccA, cbh, xbE, xbE + 256, cbh + 512);
    PHASE(1, xaB, xbB, ccB, cbh + 256, xbE + 1024, xbE + 1280, cbh + 768);
    xbE += 2048;
    cbh += 512;
  }
}

extern "C" void kernel_launch(void* const* d_in, const int* in_sizes, int n_in,
                              void* d_out, int out_size, void* d_ws, size_t ws_size,
                              hipStream_t stream) {
  const int* q = (const int*)d_in[0];
  const int* r = (const int*)d_in[1];
  const int* rg = (const int*)d_in[2];
  const int* sg = (const int*)d_in[3];
  const int* pc = (const int*)d_in[4];
  const int* srg = (const int*)d_in[5];
  const int* ssg = (const int*)d_in[6];
  const int* spc = (const int*)d_in[7];
  const float* E = (const float*)d_in[8];
  const float* Wc = (const float*)d_in[9];
  const float* Wih = (const float*)d_in[10];
  const float* Whh = (const float*)d_in[11];
  const float* bih = (const float*)d_in[12];
  const float* bhh = (const float*)d_in[13];
  const float* Wout = (const float*)d_in[14];
  const float* bout = (const float*)d_in[15];

  char* ws = (char*)d_ws;
  unsigned short* h2 = (unsigned short*)(ws);                // 64 MB
  unsigned short* Bpih = (unsigned short*)(ws + 67108864);   // 640 KB
  unsigned short* Bpout = (unsigned short*)(ws + 67764224);  // 1.25 MB
  long long* Wq = (long long*)(ws + 69074944);               // 256 KB
  float* fs = (float*)(ws + 69337088);                       // 4 KB
  int* combo = (int*)(ws + 69341184);                        // 512 KB
  int* combo2 = (int*)(ws + 69865472);                       // 512 KB
  float* WcT = (float*)(ws + 70389760);                      // 64 KB (end 70455296)

  char* dout = (char*)d_out;
  unsigned short* xg = (unsigned short*)dout;                    // 256 MB (dead until final GEMM)
  unsigned short* theta = (unsigned short*)(dout + 268435456);   // 64 MB
  unsigned short* C2 = (unsigned short*)(dout + 335544320);      // 64 MB

  k_rowmax<<<1024, 64, 0, stream>>>(Whh, fs);
  k_pack_whh_mx<<<32, 256, 0, stream>>>(Whh, fs, Wq);
  k_wct<<<64, 256, 0, stream>>>(Wc, WcT);
  k_pack_b<<<1280, 256, 0, stream>>>(Wih, Bpih, 63, 6);
  k_pack_b<<<2560, 256, 0, stream>>>(Wout, Bpout, 127, 7);
  k_theta<<<16384, 256, 0, stream>>>(q, r, rg, sg, pc, srg, ssg, spc, E, WcT, theta, C2, combo, combo2);
  k_gemm<1024, 0, 3><<<dim3(8, 1024), 256, 0, stream>>>(theta, Bpih, combo, bih, bhh, (void*)xg);
  k_lstm<<<256, 512, 0, stream>>>(xg, C2, Wq, fs, h2);
  k_gemm<2048, 1, 4><<<dim3(16, 1024), 256, 0, stream>>>(h2, Bpout, combo2, bout, nullptr, d_out);
}

// Round 13
// 1074.204 us; speedup vs baseline: 1.3434x; 1.0085x over previous
//
#include <hip/hip_runtime.h>
#include <hip/hip_bf16.h>

#define NUMC 2048

typedef short bf16x8 __attribute__((ext_vector_type(8)));
typedef float f32x4 __attribute__((ext_vector_type(4)));
typedef int i32x8 __attribute__((ext_vector_type(8)));

__device__ __forceinline__ unsigned short f2bf(float f) {
  unsigned int u = __float_as_uint(f);
  u = u + 0x7fffu + ((u >> 16) & 1u);
  return (unsigned short)(u >> 16);
}
__device__ __forceinline__ float bf2f(unsigned short s) {
  return __uint_as_float(((unsigned int)s) << 16);
}
__device__ __forceinline__ float sigm(float x) {
  return __fdividef(1.f, 1.f + __expf(-x));
}
__device__ __forceinline__ float tanh_(float x) {
  float ax = fabsf(x);
  float s = __expf(-2.f * ax);
  float ta = __fdividef(1.f - s, 1.f + s);
  return copysignf(ta, x);
}
__device__ __forceinline__ unsigned int pack2(unsigned short a, unsigned short b) {
  return (unsigned int)a | ((unsigned int)b << 16);
}
// async 16B/lane global->LDS (lds dest = wave-uniform base + lane*16)
__device__ __forceinline__ void gll16(const void* g, void* lds) {
  __builtin_amdgcn_global_load_lds(
      (const __attribute__((address_space(1))) unsigned int*)g,
      (__attribute__((address_space(3))) unsigned int*)lds, 16, 0, 0);
}

// ---- per-gate-row scale for fp8 quantization of W_hh
__global__ void k_rowmax(const float* __restrict__ Whh, float* __restrict__ fs) {
  int row = blockIdx.x;
  int l = threadIdx.x;  // 64
  float m = 0.f;
#pragma unroll
  for (int i = 0; i < 4; ++i) m = fmaxf(m, fabsf(Whh[row * 256 + i * 64 + l]));
#pragma unroll
  for (int off = 32; off > 0; off >>= 1) m = fmaxf(m, __shfl_xor(m, off));
  if (l == 0) fs[row] = (m > 0.f ? m : 1.f) * (1.f / 192.f);
}

// ---- fused prep: [0,32) pack W_hh fp8 frags; [32,96) Wc transpose;
// [96,1376) pack Wih slabs; [1376,3936) pack Wout slabs.
__global__ void k_prep(const float* __restrict__ Whh, const float* __restrict__ fs,
                       long long* __restrict__ P, const float* __restrict__ Wc,
                       float* __restrict__ WcT, const float* __restrict__ Wih,
                       unsigned short* __restrict__ Bpih, const float* __restrict__ Wout,
                       unsigned short* __restrict__ Bpout) {
  int b = blockIdx.x;
  int tid = threadIdx.x;
  if (b < 32) {
    // pack W_hh into fp8 e4m3 fragments for mfma_scale 16x16x128:
    // frag = ((w*2+nt)*4+g)*2+kt ; lane l holds 32 bytes: k = kt*128 + (l>>4)*32 + 0..31
    int e = b * 256 + tid;  // 8192 lane-slots
    int l = e & 63;
    int frag = e >> 6;
    int kt = frag & 1;
    int g = (frag >> 1) & 3;
    int nt = (frag >> 3) & 1;
    int w = frag >> 4;
    int gr = g * 256 + w * 32 + nt * 16 + (l & 15);
    int k0 = kt * 128 + (l >> 4) * 32;
    float inv = __fdividef(1.f, fs[gr]);
#pragma unroll
    for (int q = 0; q < 4; ++q) {
      unsigned long long v = 0;
#pragma unroll
      for (int jj = 0; jj < 4; ++jj) {
        float w0 = Whh[gr * 256 + k0 + q * 8 + 2 * jj] * inv;
        float w1 = Whh[gr * 256 + k0 + q * 8 + 2 * jj + 1] * inv;
        int pk = __builtin_amdgcn_cvt_pk_fp8_f32(w0, w1, 0, 0);
        v |= (unsigned long long)(unsigned)(pk & 0xffff) << (16 * jj);
      }
      P[(size_t)e * 4 + q] = (long long)v;
    }
  } else if (b < 96) {
    // WcT[t][c] = Wc[c][t]
    int e = (b - 32) * 256 + tid;  // 16384
    int t = e >> 8, c = e & 255;
    WcT[t * 256 + c] = Wc[c * 64 + t];
  } else if (b < 1376) {
    // Bpih[((ks*64 + ng)*64 + l)*8 + j] = bf16(Wih[(ng*16+(l&15))*320 + ks*32+(l>>4)*8+j])
    int e = (b - 96) * 256 + tid;
    int j = e & 7;
    int l = (e >> 3) & 63;
    int ng = (e >> 9) & 63;
    int ks = e >> 15;
    int n = ng * 16 + (l & 15);
    int k = ks * 32 + (l >> 4) * 8 + j;
    Bpih[e] = f2bf(Wih[n * 320 + k]);
  } else {
    int e = (b - 1376) * 256 + tid;
    int j = e & 7;
    int l = (e >> 3) & 63;
    int ng = (e >> 9) & 127;
    int ks = e >> 16;
    int n = ng * 16 + (l & 15);
    int k = ks * 32 + (l >> 4) * 8 + j;
    Bpout[e] = f2bf(Wout[n * 320 + k]);
  }
}

// ---- theta = bf16(E[x]*Cct), C2 = bf16(Cct_shifted), packed combos.
// Uses WcT (transposed) so every gather is a contiguous float4 pair.
__global__ void k_theta(const int* __restrict__ q, const int* __restrict__ r,
                        const int* __restrict__ rg_, const int* __restrict__ sg_,
                        const int* __restrict__ pc_, const int* __restrict__ srg_,
                        const int* __restrict__ ssg_, const int* __restrict__ spc_,
                        const float* __restrict__ E, const float* __restrict__ WcT,
                        unsigned short* __restrict__ theta, unsigned short* __restrict__ C2,
                        int* __restrict__ combo, int* __restrict__ combo2) {
  int tid = threadIdx.x;
  int row = blockIdx.x * 8 + (tid >> 5);
  int u0 = (tid & 31) * 8;
  int x = q[row] + NUMC * r[row];
  int rg = rg_[row], sg = sg_[row], pc = pc_[row];
  int g1 = srg_[row], g2 = ssg_[row], g3 = spc_[row];
  const float4* e4 = (const float4*)(E + (size_t)x * 256 + u0);
  float4 ea = e4[0], eb = e4[1];
  auto ld = [&](int rr, float4& lo, float4& hi) {
    const float4* p = (const float4*)(WcT + rr * 256 + u0);
    lo = p[0];
    hi = p[1];
  };
  float4 a0, a1, b0, b1, c0, c1, d0, d1, f0, f1, h0, h1;
  ld(rg, a0, a1);
  ld(16 + sg, b0, b1);
  ld(32 + pc, c0, c1);
  ld(g1, d0, d1);
  ld(16 + g2, f0, f1);
  ld(32 + g3, h0, h1);
  float ct[8], c2[8], ev[8];
  ct[0] = a0.x + b0.x + c0.x; ct[1] = a0.y + b0.y + c0.y;
  ct[2] = a0.z + b0.z + c0.z; ct[3] = a0.w + b0.w + c0.w;
  ct[4] = a1.x + b1.x + c1.x; ct[5] = a1.y + b1.y + c1.y;
  ct[6] = a1.z + b1.z + c1.z; ct[7] = a1.w + b1.w + c1.w;
  c2[0] = d0.x + f0.x + h0.x; c2[1] = d0.y + f0.y + h0.y;
  c2[2] = d0.z + f0.z + h0.z; c2[3] = d0.w + f0.w + h0.w;
  c2[4] = d1.x + f1.x + h1.x; c2[5] = d1.y + f1.y + h1.y;
  c2[6] = d1.z + f1.z + h1.z; c2[7] = d1.w + f1.w + h1.w;
  ev[0] = ea.x; ev[1] = ea.y; ev[2] = ea.z; ev[3] = ea.w;
  ev[4] = eb.x; ev[5] = eb.y; ev[6] = eb.z; ev[7] = eb.w;
  unsigned short tv[8], cv[8];
#pragma unroll
  for (int i = 0; i < 8; ++i) {
    tv[i] = f2bf(ev[i] * ct[i]);
    cv[i] = f2bf(c2[i]);
  }
  uint4 tvec = {pack2(tv[0], tv[1]), pack2(tv[2], tv[3]), pack2(tv[4], tv[5]), pack2(tv[6], tv[7])};
  uint4 cvec = {pack2(cv[0], cv[1]), pack2(cv[2], cv[3]), pack2(cv[4], cv[5]), pack2(cv[6], cv[7])};
  *(uint4*)(theta + (size_t)row * 256 + u0) = tvec;
  *(uint4*)(C2 + (size_t)row * 256 + u0) = cvec;
  if ((tid & 31) == 0) {
    combo[row] = (rg * 16 + sg) * 32 + pc;
    combo2[row] = (g1 * 16 + g2) * 32 + g3;
  }
}

__device__ __forceinline__ uint4 onehot8(int k0, int rg, int sg, int pc) {
  unsigned vv[8];
#pragma unroll
  for (int j = 0; j < 8; ++j) {
    int k = k0 + j;
    vv[j] = (k == rg || k == sg || k == pc) ? 0x3F80u : 0u;
  }
  uint4 rr;
  rr.x = vv[0] | (vv[1] << 16);
  rr.y = vv[2] | (vv[3] << 16);
  rr.z = vv[4] | (vv[5] << 16);
  rr.w = vv[6] | (vv[7] << 16);
  return rr;
}

// ---- 128x128xK=320 bf16 MFMA GEMM, TRIPLE-buffered counted-vmcnt pipeline:
// STAGE(ks+2) issued early -> every load has ~2 MFMA phases to land.
// barrier #1 = vmcnt(N)+s_barrier waits ONLY stage(ks); N = loads of stages ks+1,ks+2
// (8,8,8,8,8,8,6,4,2,0). barrier #2 = lgkmcnt(0)+s_barrier (buffer reuse, no vm drain;
// skipped on the last iteration -- epilogue never touches LDS).
// MODE 0: xg = [A|ct]*B^T + b_ih + b_hh -> bf16.  MODE 1: y = sigmoid(..+b_out) -> f32
template <int NTOT, int MODE, int LOGGX>
__global__ __launch_bounds__(256) void k_gemm(
    const unsigned short* __restrict__ A, const unsigned short* __restrict__ Bp,
    const int* __restrict__ combo, const float* __restrict__ bias1,
    const float* __restrict__ bias2, void* __restrict__ Out) {
  __shared__ __align__(16) unsigned short As[3][4096];
  __shared__ __align__(16) unsigned short Bs[3][4096];
  const int tid = threadIdx.x;
  const int w = tid >> 6, l = tid & 63;
  const int wm = w >> 1, wn = w & 1;
  constexpr int NG = NTOT / 16;

  int id = blockIdx.y * (1 << LOGGX) + blockIdx.x;
  int Nbase = ((id >> 3) & ((1 << LOGGX) - 1)) * 128;
  int Mbase = ((((id >> (3 + LOGGX)) << 3) | (id & 7))) * 128;

  f32x4 acc[4][4];
#pragma unroll
  for (int i = 0; i < 4; ++i)
#pragma unroll
    for (int j = 0; j < 4; ++j) acc[i][j] = (f32x4){0.f, 0.f, 0.f, 0.f};

  // staging addresses: wave w owns slabs 2w, 2w+1 of both A and B
  const unsigned short* gA = A + (size_t)(Mbase + (2 * w) * 16 + (l & 15)) * 256 + (l >> 4) * 8;
  const unsigned short* gB = Bp + ((size_t)(Nbase / 16 + 2 * w) * 64 + l) * 8;

  // one-hot synth params (K tail)
  const int arow = tid >> 1;
  const int agp = (tid & 1) * 2;
  const int a_ch = arow >> 4;
  const int a_ls0 = (arow & 15) | (agp << 4);
  const int a_ls1 = (arow & 15) | ((agp + 1) << 4);
  const int cmb = combo[Mbase + arow];
  const int rg = cmb >> 9, sg = 16 + ((cmb >> 5) & 15), pc = 32 + (cmb & 31);

  // STAGE K-step ks into buffer nb.  vmem loads/wave: ks<8 -> 4, ks in {8,9} -> 2.
  auto STAGE = [&](int ks, int nb) {
    if (ks < 8) {
      gll16(gA + ks * 32, &As[nb][(2 * w) * 512]);
      gll16(gA + ks * 32 + 16 * 256, &As[nb][(2 * w + 1) * 512]);
    } else {
      int k0 = (ks - 8) * 32 + agp * 8;
      uint4 av0 = onehot8(k0, rg, sg, pc);
      uint4 av1 = onehot8(k0 + 8, rg, sg, pc);
      *(uint4*)&As[nb][(a_ch * 64 + a_ls0) * 8] = av0;
      *(uint4*)&As[nb][(a_ch * 64 + a_ls1) * 8] = av1;
    }
    gll16(gB + (size_t)ks * NG * 512, &Bs[nb][(2 * w) * 512]);
    gll16(gB + (size_t)ks * NG * 512 + 64 * 8, &Bs[nb][(2 * w + 1) * 512]);
  };

  STAGE(0, 0);
  STAGE(1, 1);

#pragma unroll
  for (int ks = 0; ks < 10; ++ks) {
    const int b = ks % 3;
    if (ks < 8) STAGE(ks + 2, (ks + 2) % 3);  // depth-2 prefetch
    // barrier #1: wait only stage(ks)'s loads (stages ks+1, ks+2 stay in flight)
    if (ks <= 5)
      asm volatile("s_waitcnt vmcnt(8)\ns_barrier" ::: "memory");
    else if (ks == 6)
      asm volatile("s_waitcnt vmcnt(6)\ns_barrier" ::: "memory");
    else if (ks == 7)
      asm volatile("s_waitcnt vmcnt(4)\ns_barrier" ::: "memory");
    else if (ks == 8)
      asm volatile("s_waitcnt vmcnt(2)\ns_barrier" ::: "memory");
    else
      asm volatile("s_waitcnt vmcnt(0)\ns_barrier" ::: "memory");
    bf16x8 bfr[4];
#pragma unroll
    for (int ni = 0; ni < 4; ++ni)
      bfr[ni] = *(const bf16x8*)&Bs[b][((wn * 4 + ni) * 64 + l) * 8];
#pragma unroll
    for (int mi = 0; mi < 4; ++mi) {
      bf16x8 af = *(const bf16x8*)&As[b][((wm * 4 + mi) * 64 + l) * 8];
#pragma unroll
      for (int ni = 0; ni < 4; ++ni)
        acc[mi][ni] = __builtin_amdgcn_mfma_f32_16x16x32_bf16(af, bfr[ni], acc[mi][ni], 0, 0, 0);
    }
    // barrier #2: all waves done reading buf b (LDS-only wait; vm stays in flight)
    if (ks < 9) asm volatile("s_waitcnt lgkmcnt(0)\ns_barrier" ::: "memory");
  }

  int lh = l >> 4, col = l & 15;
  float badd[4];
#pragma unroll
  for (int ni = 0; ni < 4; ++ni) {
    int gcol = Nbase + wn * 64 + ni * 16 + col;
    badd[ni] = bias1[gcol] + (MODE == 0 ? bias2[gcol] : 0.f);
  }
#pragma unroll
  for (int mi = 0; mi < 4; ++mi) {
    int grow0 = Mbase + wm * 64 + mi * 16 + lh * 4;
#pragma unroll
    for (int rr = 0; rr < 4; ++rr) {
      int grow = grow0 + rr;
#pragma unroll
      for (int ni = 0; ni < 4; ++ni) {
        int gcol = Nbase + wn * 64 + ni * 16 + col;
        float v = acc[mi][ni][rr] + badd[ni];
        if (MODE == 0) {
          ((unsigned short*)Out)[(size_t)grow * NTOT + gcol] = f2bf(v);
        } else {
          ((float*)Out)[(size_t)grow * NTOT + gcol] = sigm(v);
        }
      }
    }
  }
}

// ---- LSTM: 256 independent blocks x 1 batch row; all 1024 gates per block.
// W_hh fp8 in VGPRs, mfma_scale 16x16x128; running-sum acc (no reset); gate-spread
// epilogue (2 gates/lane); lgkm-only barriers; 2-step unrolled named prefetch regs.
__global__ __launch_bounds__(512, 1) void k_lstm(
    const unsigned short* __restrict__ xg, const unsigned short* __restrict__ C2,
    const long long* __restrict__ Wq, const float* __restrict__ fs,
    unsigned short* __restrict__ h2) {
  __shared__ __align__(16) char hq[2][4224];
  const int tid = threadIdx.x;
  const int w = tid >> 6, l = tid & 63;
  const int col = l & 15;
  const int half = (l >> 4) & 1;  // 0: i,f lanes   1: g,o lanes
  const int ntsel = l >> 5;
  const int blk = blockIdx.x;  // 256 blocks

  i32x8 wreg[2][4][2];
#pragma unroll
  for (int nt = 0; nt < 2; ++nt)
#pragma unroll
    for (int g = 0; g < 4; ++g)
#pragma unroll
      for (int kt = 0; kt < 2; ++kt)
        wreg[nt][g][kt] =
            ((const i32x8*)Wq)[(((w * 2 + nt) * 4 + g) * 2 + kt) * 64 + l];

  const int u = w * 32 + ntsel * 16 + col;
  const float fsa = fs[(half * 2 + 0) * 256 + u];
  const float fsb = fs[(half * 2 + 1) * 256 + u];
  const float AA = half ? 2.f : 1.f;
  const float BB = half ? -1.f : 0.f;
  const float SS = half ? 2.f : 1.f;

  {
    uint4 zz = {0u, 0u, 0u, 0u};
    ((uint4*)hq)[tid] = zz;
    if (tid < 16) ((uint4*)hq)[512 + tid] = zz;
  }

  const unsigned bg = (unsigned)blk;
  const unsigned xg0 = (bg << 19) + (unsigned)((half * 2) * 256 + u);
  const unsigned c0 = (bg << 17) + (unsigned)u;

  // preload t=0 (A regs) and t=1 (B regs)
  unsigned short xaA = xg[xg0], xbA = xg[xg0 + 256];
  unsigned short ccA = C2[c0];
  unsigned short xaB = xg[xg0 + 1024], xbB = xg[xg0 + 1280];
  unsigned short ccB = C2[c0 + 256];
  unsigned xbE = xg0 + 2048;  // xg issue addr for even phase (t2+2)
  unsigned cbh = c0;          // h2 store addr for even phase (t2)

  __syncthreads();

  float cst = 0.f, SoldA = 0.f, SoldB = 0.f;
  f32x4 acc[2][4];
#pragma unroll
  for (int nt = 0; nt < 2; ++nt)
#pragma unroll
    for (int g = 0; g < 4; ++g) acc[nt][g] = (f32x4){0.f, 0.f, 0.f, 0.f};

  auto PHASE = [&](int PB, unsigned short& XA, unsigned short& XB, unsigned short& CC,
                   unsigned h2addr, unsigned xissA, unsigned xissB, unsigned ciss) {
#pragma unroll
    for (int kt = 0; kt < 2; ++kt) {
      int ab = col * 264 + kt * 128 + (l >> 4) * 32;
      uint4 a0 = *(const uint4*)&hq[PB][ab];
      uint4 a1 = *(const uint4*)&hq[PB][ab + 16];
      i32x8 av;
      av[0] = (int)a0.x; av[1] = (int)a0.y; av[2] = (int)a0.z; av[3] = (int)a0.w;
      av[4] = (int)a1.x; av[5] = (int)a1.y; av[6] = (int)a1.z; av[7] = (int)a1.w;
#pragma unroll
      for (int nt = 0; nt < 2; ++nt)
#pragma unroll
        for (int g = 0; g < 4; ++g)
          acc[nt][g] = __builtin_amdgcn_mfma_scale_f32_16x16x128_f8f6f4(
              av, wreg[nt][g][kt], acc[nt][g], 0, 0, 0, 0x7F7F7F7F, 0, 0x7F7F7F7F);
    }
    float m0 = __uint_as_float(
        __builtin_amdgcn_permlane32_swap(__float_as_uint(acc[0][0][0]),
                                         __float_as_uint(acc[1][0][0]), false, false)[0]);
    float m1 = __uint_as_float(
        __builtin_amdgcn_permlane32_swap(__float_as_uint(acc[0][1][0]),
                                         __float_as_uint(acc[1][1][0]), false, false)[0]);
    float m2 = __uint_as_float(
        __builtin_amdgcn_permlane32_swap(__float_as_uint(acc[0][2][0]),
                                         __float_as_uint(acc[1][2][0]), false, false)[0]);
    float m3 = __uint_as_float(
        __builtin_amdgcn_permlane32_swap(__float_as_uint(acc[0][3][0]),
                                         __float_as_uint(acc[1][3][0]), false, false)[0]);
    float mm2 = __shfl_xor(m2, 16);
    float mm3 = __shfl_xor(m3, 16);
    float a_ = half ? mm2 : m0;
    float b_ = half ? mm3 : m1;
    float pa = a_ - SoldA;
    SoldA = a_;
    float pb_ = b_ - SoldB;
    SoldB = b_;
    float va = pa * fsa + bf2f(XA);
    float vb = pb_ * fsb + bf2f(XB);
    float ra = AA * __fdividef(1.f, 1.f + __expf(-SS * va)) + BB;
    float rb = sigm(vb);
    float si = __shfl_xor(ra, 16);
    float sf = __shfl_xor(rb, 16);
    float cv = sf * cst + si * ra;
    cst = cv;
    float th = tanh_(cv);
    float hv = rb * th;
    if (half) {
      // LDS write first (its completion gates the barrier), then global store
      int pk = __builtin_amdgcn_cvt_pk_fp8_f32(hv, hv, 0, 0);
      hq[PB ^ 1][u] = (char)(pk & 255);
      h2[h2addr] = f2bf(hv * bf2f(CC));
    }
    // prefetch t+2 into freed regs (never drained at the barrier below)
    XA = xg[xissA];
    XB = xg[xissB];
    CC = C2[ciss];
    asm volatile("s_waitcnt lgkmcnt(0)\ns_barrier" ::: "memory");
  };

#pragma unroll 1
  for (int t2 = 0; t2 < 512; t2 += 2) {
    PHASE(0, xaA, xbA, ccA, cbh, xbE, xbE + 256, cbh + 512);
    PHASE(1, xaB, xbB, ccB, cbh + 256, xbE + 1024, xbE + 1280, cbh + 768);
    xbE += 2048;
    cbh += 512;
  }
}

extern "C" void kernel_launch(void* const* d_in, const int* in_sizes, int n_in,
                              void* d_out, int out_size, void* d_ws, size_t ws_size,
                              hipStream_t stream) {
  const int* q = (const int*)d_in[0];
  const int* r = (const int*)d_in[1];
  const int* rg = (const int*)d_in[2];
  const int* sg = (const int*)d_in[3];
  const int* pc = (const int*)d_in[4];
  const int* srg = (const int*)d_in[5];
  const int* ssg = (const int*)d_in[6];
  const int* spc = (const int*)d_in[7];
  const float* E = (const float*)d_in[8];
  const float* Wc = (const float*)d_in[9];
  const float* Wih = (const float*)d_in[10];
  const float* Whh = (const float*)d_in[11];
  const float* bih = (const float*)d_in[12];
  const float* bhh = (const float*)d_in[13];
  const float* Wout = (const float*)d_in[14];
  const float* bout = (const float*)d_in[15];

  char* ws = (char*)d_ws;
  unsigned short* h2 = (unsigned short*)(ws);                // 64 MB
  unsigned short* Bpih = (unsigned short*)(ws + 67108864);   // 640 KB
  unsigned short* Bpout = (unsigned short*)(ws + 67764224);  // 1.25 MB
  long long* Wq = (long long*)(ws + 69074944);               // 256 KB
  float* fs = (float*)(ws + 69337088);                       // 4 KB
  int* combo = (int*)(ws + 69341184);                        // 512 KB
  int* combo2 = (int*)(ws + 69865472);                       // 512 KB
  float* WcT = (float*)(ws + 70389760);                      // 64 KB (end 70455296)

  char* dout = (char*)d_out;
  unsigned short* xg = (unsigned short*)dout;                    // 256 MB (dead until final GEMM)
  unsigned short* theta = (unsigned short*)(dout + 268435456);   // 64 MB
  unsigned short* C2 = (unsigned short*)(dout + 335544320);      // 64 MB

  k_rowmax<<<1024, 64, 0, stream>>>(Whh, fs);
  k_prep<<<3936, 256, 0, stream>>>(Whh, fs, Wq, Wc, WcT, Wih, Bpih, Wout, Bpout);
  k_theta<<<16384, 256, 0, stream>>>(q, r, rg, sg, pc, srg, ssg, spc, E, WcT, theta, C2, combo, combo2);
  k_gemm<1024, 0, 3><<<dim3(8, 1024), 256, 0, stream>>>(theta, Bpih, combo, bih, bhh, (void*)xg);
  k_lstm<<<256, 512, 0, stream>>>(xg, C2, Wq, fs, h2);
  k_gemm<2048, 1, 4><<<dim3(16, 1024), 256, 0, stream>>>(h2, Bpout, combo2, bout, nullptr, d_out);
}